// Round 3
// baseline (284.282 us; speedup 1.0000x reference)
//
#include <hip/hip_runtime.h>
#include <hip/hip_bf16.h>

typedef unsigned short u16;
typedef __attribute__((ext_vector_type(8))) short short8;
typedef __attribute__((ext_vector_type(8))) unsigned short ushort8;
typedef __attribute__((ext_vector_type(4))) float f32x4;

#define GLB_CAST(p) ((const __attribute__((address_space(1))) unsigned int*)(p))
#define LDS_CAST(p) ((__attribute__((address_space(3))) unsigned int*)(p))

__device__ __forceinline__ void gl_lds16(const void* g, void* l) {
  __builtin_amdgcn_global_load_lds(GLB_CAST(g), LDS_CAST(l), 16, 0, 0);
}

__device__ __forceinline__ u16 f2bf(float f) {
  __hip_bfloat16 b = __float2bfloat16(f);           // RNE, 1 VALU on gfx950
  return __builtin_bit_cast(u16, b);
}

// ---------------- prep: fp32 -> bf16 (vectorized) ----------------
__global__ void cvt_f32_bf16_k(const float* __restrict__ in,
                               u16* __restrict__ out, int n8) {
  typedef __attribute__((ext_vector_type(4))) float f4;
  int idx = blockIdx.x * blockDim.x + threadIdx.x;
  int stride = gridDim.x * blockDim.x;
  for (int i = idx; i < n8; i += stride) {
    f4 a = ((const f4*)in)[2 * i];
    f4 b = ((const f4*)in)[2 * i + 1];
    ushort8 o;
    o[0] = f2bf(a[0]); o[1] = f2bf(a[1]); o[2] = f2bf(a[2]); o[3] = f2bf(a[3]);
    o[4] = f2bf(b[0]); o[5] = f2bf(b[1]); o[6] = f2bf(b[2]); o[7] = f2bf(b[3]);
    ((ushort8*)out)[i] = o;
  }
}

// ---------------- prep: W [R][C] f32 -> Wt [C][R] bf16 ----------------
__global__ void transpose_cvt_k(const float* __restrict__ in,
                                u16* __restrict__ out, int R, int C) {
  __shared__ float tile[32][33];
  int c0 = blockIdx.x * 32, r0 = blockIdx.y * 32;
  int tx = threadIdx.x, ty = threadIdx.y;     // 32 x 8
#pragma unroll
  for (int i = 0; i < 32; i += 8)
    tile[ty + i][tx] = in[(size_t)(r0 + ty + i) * C + c0 + tx];
  __syncthreads();
#pragma unroll
  for (int i = 0; i < 32; i += 8)
    out[(size_t)(c0 + ty + i) * R + r0 + tx] = f2bf(tile[tx][ty + i]);
}

// ---------------- GEMM (A [M x K] bf16, Bt [N x K] bf16) ----------------
// 128x128 tile, BK=32, dbuf LDS = 32KB total -> 5 blocks/CU.
// T2 swizzle for 64B rows: key ((r>>1)&3)<<4, inverse-swizzled global source.
// XCD-bijective grid swizzle, n fastest within each XCD band.
// EPI=1: qkv epilogue via LDS repack (+bias, wide stores to q/k/vT bf16).
// EPI=2: proj epilogue (+bias, direct f32 stores).
template <int EPI>
__global__ __launch_bounds__(256, 5) void gemm_bt_k(
    const u16* __restrict__ A, const u16* __restrict__ Bt, int K, int N,
    const float* __restrict__ bias,
    u16* __restrict__ oQ, u16* __restrict__ oK, u16* __restrict__ oVT,
    float* __restrict__ oF) {
  __shared__ char smem[32768];
  u16* lA = (u16*)smem;              // [2][128*32]
  u16* lB = (u16*)(smem + 16384);    // [2][128*32]
  u16* Cs = (u16*)smem;              // epilogue C-tile [128][128] bf16 (reuse)

  const int tid = threadIdx.x;
  const int nwg = gridDim.x;
  const int ntn = N >> 7;
  const int per = nwg >> 3;
  const int idx = (blockIdx.x & 7) * per + (blockIdx.x >> 3);
  const int m0 = (idx / ntn) * 128;
  const int n0 = (idx % ntn) * 128;

  const int lane = tid & 63, wid = tid >> 6;
  const int lo = lane & 15, hi = lane >> 4;
  const int wr = wid >> 1, wc = wid & 1;

  const f32x4 Z4 = {0.f, 0.f, 0.f, 0.f};
  f32x4 acc[4][4];
#pragma unroll
  for (int m = 0; m < 4; ++m)
#pragma unroll
    for (int n = 0; n < 4; ++n) acc[m][n] = Z4;

  // stage K-step kt into buffer buf (8KB A + 8KB B), src col-chunk inverse-swizzled
  auto stage = [&](int buf, int kt) {
#pragma unroll
    for (int it = 0; it < 2; ++it) {
      int c = tid + it * 256;            // 512 chunks of 16B per tile
      int r = c >> 2, cc = c & 3;
      int cs = cc ^ ((r >> 1) & 3);
      gl_lds16(A + (size_t)(m0 + r) * K + kt + cs * 8, lA + buf * 4096 + c * 8);
      gl_lds16(Bt + (size_t)(n0 + r) * K + kt + cs * 8, lB + buf * 4096 + c * 8);
    }
  };

  const int NKT = K >> 5;                // 12 for K=384
  const int rk = ((lo >> 1) & 3) << 4;   // read-side swizzle key (thread-const)
  stage(0, 0);
  __syncthreads();
  int cur = 0;
  for (int t = 0; t < NKT; ++t) {
    if (t + 1 < NKT) stage(cur ^ 1, (t + 1) << 5);   // prefetch overlaps compute
    const char* pa = (const char*)(lA + cur * 4096) + (wr * 64 + lo) * 64 + ((hi * 16) ^ rk);
    const char* pb = (const char*)(lB + cur * 4096) + (wc * 64 + lo) * 64 + ((hi * 16) ^ rk);
    short8 af[4], bf[4];
#pragma unroll
    for (int m = 0; m < 4; ++m) af[m] = *(const short8*)(pa + m * 1024);
#pragma unroll
    for (int n = 0; n < 4; ++n) bf[n] = *(const short8*)(pb + n * 1024);
#pragma unroll
    for (int m = 0; m < 4; ++m)
#pragma unroll
      for (int n = 0; n < 4; ++n)
        acc[m][n] = __builtin_amdgcn_mfma_f32_16x16x32_bf16(af[m], bf[n], acc[m][n], 0, 0, 0);
    __syncthreads();
    cur ^= 1;
  }

  // bias per n-column group
  float bs[4];
#pragma unroll
  for (int n = 0; n < 4; ++n) bs[n] = bias[n0 + wc * 64 + n * 16 + lo];

  if (EPI == 2) {
    // direct f32 stores: [M, N] row-major
    const int rbase = m0 + wr * 64;
    const int cbase = n0 + wc * 64;
#pragma unroll
    for (int n = 0; n < 4; ++n) {
      int gn = cbase + n * 16 + lo;
#pragma unroll
      for (int m = 0; m < 4; ++m)
#pragma unroll
        for (int r = 0; r < 4; ++r) {
          int gm = rbase + m * 16 + hi * 4 + r;
          oF[(size_t)gm * N + gn] = acc[m][n][r] + bs[n];
        }
    }
    return;
  }

  // EPI==1: repack through LDS, then wide coalesced stores.
  u16* cw = Cs + (size_t)(wr * 64 + hi * 4) * 128 + wc * 64 + lo;
#pragma unroll
  for (int m = 0; m < 4; ++m)
#pragma unroll
    for (int n = 0; n < 4; ++n)
#pragma unroll
      for (int r = 0; r < 4; ++r)
        cw[m * 2048 + r * 128 + n * 16] = f2bf(acc[m][n][r] + bs[n]);
  __syncthreads();

  const int region = n0 / 384;           // 0:q  1:k  2:v
  const int nbase = n0 % 384;
  if (region < 2) {
    u16* dst = region ? oK : oQ;
#pragma unroll
    for (int it = 0; it < 8; ++it) {
      int c = tid + it * 256;            // 2048 chunks of 16B
      int rho = c >> 4, c16 = c & 15;
      short8 v = *(const short8*)((const char*)Cs + rho * 256 + c16 * 16);
      int gm = m0 + rho;
      int b = gm >> 8, tt = gm & 255;
      int hc = nbase + c16 * 8;
      int hh = hc >> 6, d0 = hc & 63;
      *(short8*)(dst + ((size_t)((b * 6 + hh) << 8 | tt) << 6) + d0) = v;
    }
  } else {
    // vT [b,h,d,t]: transpose-read from Cs
    const int chi = tid & 127;           // col in tile (d-direction)
    const int tr0 = (tid >> 7) * 64;     // row half (t-direction)
    int hc = nbase + chi;
    int hh = hc >> 6, d = hc & 63;
    int b = m0 >> 8;
    int tg0 = (m0 & 255) + tr0;
    u16* dst = oVT + ((size_t)((b * 6 + hh) << 6 | d) << 8) + tg0;
#pragma unroll
    for (int s = 0; s < 8; ++s) {
      ushort8 v;
#pragma unroll
      for (int j = 0; j < 8; ++j)
        v[j] = Cs[(tr0 + s * 8 + j) * 128 + chi];
      *(ushort8*)(dst + s * 8) = v;
    }
  }
}

// ---------------- windowed causal attention ----------------
// grid: (B*H*4) blocks; block = 4 waves; block handles 64 queries, 128 candidate keys.
__global__ __launch_bounds__(256) void attn_k(
    const u16* __restrict__ Qb, const u16* __restrict__ Kb,
    const u16* __restrict__ VTb, const float* __restrict__ gate,
    u16* __restrict__ Ao) {
  __shared__ u16 Ks[128 * 64];      // [key][d]   swizzled, 16KB
  __shared__ u16 Vs[64 * 128];      // [d][key]   swizzled, 16KB
  __shared__ u16 Ps[4][16 * 128];   // per-wave P [q][key] swizzled, 16KB
  const int bx = blockIdx.x;
  const int qt = bx & 3, bh = bx >> 2;
  const int h = bh % 6, b = bh / 6;
  const int i0 = qt * 64, j0 = i0 - 64;
  const int tid = threadIdx.x, w = tid >> 6, lane = tid & 63;
  const int lo = lane & 15, hi = lane >> 4;

  const u16* Kh = Kb + (size_t)bh * (256 * 64);
  const u16* Vh = VTb + (size_t)bh * (64 * 256);
  const u16* Qh = Qb + (size_t)bh * (256 * 64);

  // stage K [128 x 64]: linear LDS dest, inverse-swizzled global source
#pragma unroll
  for (int it = 0; it < 4; ++it) {
    int chunk = tid + it * 256;
    int row = chunk >> 3, cc = chunk & 7;
    int csrc = cc ^ (row & 7);
    int j = j0 + row; if (j < 0) j = 0;       // masked later via P=0
    gl_lds16(Kh + j * 64 + csrc * 8, Ks + chunk * 8);
  }
  // stage V^T [64 x 128]
#pragma unroll
  for (int it = 0; it < 4; ++it) {
    int chunk = tid + it * 256;
    int d = chunk >> 4, kc = chunk & 15;
    int ksrc = kc ^ (d & 7);
    int j = j0 + ksrc * 8; if (j < 0) j = 0;  // whole-chunk invalid only
    gl_lds16(Vh + d * 256 + j, Vs + chunk * 8);
  }

  // Q fragments direct from global
  const int iq = i0 + w * 16 + lo;
  short8 aq0 = *(const short8*)(Qh + iq * 64 + hi * 8);
  short8 aq1 = *(const short8*)(Qh + iq * 64 + 32 + hi * 8);

  __syncthreads();

  // S = Q K^T : wave computes [16 q x 128 keys]
  const f32x4 Z4 = {0.f, 0.f, 0.f, 0.f};
  f32x4 accS[8];
#pragma unroll
  for (int t = 0; t < 8; ++t) accS[t] = Z4;
#pragma unroll
  for (int t = 0; t < 8; ++t) {
    int key = t * 16 + lo;
    int base = key * 128;
    int sw = (key & 7) << 4;
    short8 bk0 = *(const short8*)((const char*)Ks + ((base + hi * 16) ^ sw));
    short8 bk1 = *(const short8*)((const char*)Ks + ((base + 64 + hi * 16) ^ sw));
    accS[t] = __builtin_amdgcn_mfma_f32_16x16x32_bf16(aq0, bk0, accS[t], 0, 0, 0);
    accS[t] = __builtin_amdgcn_mfma_f32_16x16x32_bf16(aq1, bk1, accS[t], 0, 0, 0);
  }

  // masked softmax (per row; cols spread over 16-lane group x 8 tiles)
  float pv[4][8];
  float rinv[4];
#pragma unroll
  for (int r = 0; r < 4; ++r) {
    int i = i0 + w * 16 + hi * 4 + r;
    float mx = -1e30f;
    float vals[8];
#pragma unroll
    for (int t = 0; t < 8; ++t) {
      int j = j0 + t * 16 + lo;
      float s = accS[t][r] * 0.125f;          // 1/sqrt(64)
      bool ok = (j >= 0) && (j <= i) && (j >= i - 64);
      vals[t] = ok ? s : -1e30f;
      mx = fmaxf(mx, vals[t]);
    }
#pragma unroll
    for (int off = 1; off < 16; off <<= 1) mx = fmaxf(mx, __shfl_xor(mx, off));
    float sum = 0.f;
#pragma unroll
    for (int t = 0; t < 8; ++t) {
      float p = __expf(vals[t] - mx);
      pv[r][t] = p;
      sum += p;
    }
#pragma unroll
    for (int off = 1; off < 16; off <<= 1) sum += __shfl_xor(sum, off);
    rinv[r] = 1.0f / sum;
  }

  // P (unnormalized, bf16) -> per-wave LDS, swizzled
  u16* Pw = Ps[w];
#pragma unroll
  for (int r = 0; r < 4; ++r) {
    int ql = hi * 4 + r;
    int sw = (ql & 7) << 4;
#pragma unroll
    for (int t = 0; t < 8; ++t) {
      int off = (ql * 256 + (t * 16 + lo) * 2) ^ sw;
      *(u16*)((char*)Pw + off) = f2bf(pv[r][t]);
    }
  }

  // O = P V : [16 q x 64 d]
  f32x4 accO[4];
#pragma unroll
  for (int dt = 0; dt < 4; ++dt) accO[dt] = Z4;
#pragma unroll
  for (int ks = 0; ks < 4; ++ks) {
    int offA = (lo * 256 + ks * 64 + hi * 16) ^ ((lo & 7) << 4);
    short8 ap = *(const short8*)((const char*)Pw + offA);
#pragma unroll
    for (int dt = 0; dt < 4; ++dt) {
      int d = dt * 16 + lo;
      int offB = (d * 256 + ks * 64 + hi * 16) ^ ((d & 7) << 4);
      short8 bv = *(const short8*)((const char*)Vs + offB);
      accO[dt] = __builtin_amdgcn_mfma_f32_16x16x32_bf16(ap, bv, accO[dt], 0, 0, 0);
    }
  }

  // epilogue: normalize, gate, write bf16 [b, t, h*64+d]
#pragma unroll
  for (int dt = 0; dt < 4; ++dt) {
    int d = dt * 16 + lo;
    float gg = gate[h * 64 + d];
#pragma unroll
    for (int r = 0; r < 4; ++r) {
      int i = i0 + w * 16 + hi * 4 + r;
      float v = accO[dt][r] * rinv[r] * gg;
      Ao[(size_t)(b * 256 + i) * 384 + h * 64 + d] = f2bf(v);
    }
  }
}

// ---------------- launch ----------------
extern "C" void kernel_launch(void* const* d_in, const int* in_sizes, int n_in,
                              void* d_out, int out_size, void* d_ws, size_t ws_size,
                              hipStream_t stream) {
  const float* x      = (const float*)d_in[0];
  const float* qkv_w  = (const float*)d_in[1];
  const float* qkv_b  = (const float*)d_in[2];
  const float* proj_w = (const float*)d_in[3];
  const float* proj_b = (const float*)d_in[4];
  const float* gate   = (const float*)d_in[5];
  float* out = (float*)d_out;

  char* ws = (char*)d_ws;
  u16* x_bf = (u16*)ws;
  u16* vT   = (u16*)(ws + 50331648);
  u16* w1T  = (u16*)(ws + 100663296);
  u16* pT   = (u16*)(ws + 101548032);
  // d_out (100663296 B) doubles as q+k scratch until GEMM2 overwrites it
  u16* qbuf = (u16*)d_out;
  u16* kbuf = (u16*)((char*)d_out + 50331648);
  u16* att  = x_bf;   // x_bf dead after GEMM1

  cvt_f32_bf16_k<<<2048, 256, 0, stream>>>(x, x_bf, 25165824 / 8);
  transpose_cvt_k<<<dim3(1152 / 32, 384 / 32), dim3(32, 8), 0, stream>>>(qkv_w, w1T, 384, 1152);
  transpose_cvt_k<<<dim3(384 / 32, 384 / 32), dim3(32, 8), 0, stream>>>(proj_w, pT, 384, 384);

  gemm_bt_k<1><<<4608, 256, 0, stream>>>(x_bf, w1T, 384, 1152, qkv_b,
                                         qbuf, kbuf, vT, nullptr);
  attn_k<<<256 * 6 * 4, 256, 0, stream>>>(qbuf, kbuf, vT, gate, att);
  gemm_bt_k<2><<<1536, 256, 0, stream>>>(att, pT, 384, 384, proj_b,
                                         nullptr, nullptr, nullptr, out);
}

// Round 4
// 208.675 us; speedup vs baseline: 1.3623x; 1.3623x over previous
//
#include <hip/hip_runtime.h>
#include <hip/hip_bf16.h>

typedef unsigned short u16;
typedef __attribute__((ext_vector_type(8))) short short8;
typedef __attribute__((ext_vector_type(8))) unsigned short ushort8;
typedef __attribute__((ext_vector_type(4))) float f32x4;

#define GLB_CAST(p) ((const __attribute__((address_space(1))) unsigned int*)(p))
#define LDS_CAST(p) ((__attribute__((address_space(3))) unsigned int*)(p))

__device__ __forceinline__ void gl_lds16(const void* g, void* l) {
  __builtin_amdgcn_global_load_lds(GLB_CAST(g), LDS_CAST(l), 16, 0, 0);
}

__device__ __forceinline__ u16 f2bf(float f) {
  __hip_bfloat16 b = __float2bfloat16(f);           // RNE
  return __builtin_bit_cast(u16, b);
}

// ---------------- prep: W [R][C] f32 -> Wt [C][R] bf16 ----------------
__global__ void transpose_cvt_k(const float* __restrict__ in,
                                u16* __restrict__ out, int R, int C) {
  __shared__ float tile[32][33];
  int c0 = blockIdx.x * 32, r0 = blockIdx.y * 32;
  int tx = threadIdx.x, ty = threadIdx.y;     // 32 x 8
#pragma unroll
  for (int i = 0; i < 32; i += 8)
    tile[ty + i][tx] = in[(size_t)(r0 + ty + i) * C + c0 + tx];
  __syncthreads();
#pragma unroll
  for (int i = 0; i < 32; i += 8)
    out[(size_t)(c0 + ty + i) * R + r0 + tx] = f2bf(tile[tx][ty + i]);
}

// ---------------- GEMM1: qkv = x(f32) @ w1T^T, fused cvt, epilogue scatter ----------------
// 128x128 tile, BK=64, dbuf 64KB LDS (2 blk/CU). A: f32 global->reg->bf16->ds_write (swizzled).
// B: global_load_lds (inverse-swizzled source). XCD-bijective grid swizzle.
__global__ __launch_bounds__(256) void gemm_qkv_k(
    const float* __restrict__ X, const u16* __restrict__ Bt,
    const float* __restrict__ bias,
    u16* __restrict__ oQ, u16* __restrict__ oK, u16* __restrict__ oVT) {
  constexpr int K = 384, NTN = 9;
  __shared__ char smem[65536];
  u16* lA = (u16*)smem;              // [2][8192] u16 (16KB each)
  u16* lB = (u16*)(smem + 32768);    // [2][8192]
  u16* Cs = (u16*)smem;              // epilogue [128][128] bf16 (32KB, reuse)

  const int tid = threadIdx.x;
  const int per = gridDim.x >> 3;
  const int idx = (blockIdx.x & 7) * per + (blockIdx.x >> 3);
  const int m0 = (idx / NTN) * 128;
  const int n0 = (idx % NTN) * 128;
  const int lane = tid & 63, wid = tid >> 6;
  const int lo = lane & 15, hi = lane >> 4;
  const int wr = wid >> 1, wc = wid & 1;

  // per-thread staging coords (thread-constant)
  const int rb = tid >> 3;              // base row (chunk it adds 32)
  const int cb = tid & 7;               // col chunk
  const int akey = (rb & 7) << 4;       // A write swizzle key (r&7 invariant over it)
  const int csb = cb ^ (rb & 7);        // B source col swizzle (invariant over it)

  // hoisted global pointers
  const float* pxa[4];
  const u16* pxb[4];
#pragma unroll
  for (int it = 0; it < 4; ++it) {
    pxa[it] = X + (size_t)(m0 + rb + it * 32) * K + cb * 8;
    pxb[it] = Bt + (size_t)(n0 + rb + it * 32) * K + csb * 8;
  }
  // hoisted LDS byte offsets
  int awoff[4], bwoff[4];
#pragma unroll
  for (int it = 0; it < 4; ++it) {
    awoff[it] = (rb + it * 32) * 128 + ((cb * 16) ^ akey);
    bwoff[it] = (tid + it * 256) * 16;
  }

  typedef __attribute__((ext_vector_type(4))) float f4;
  f4 areg[4][2];

  auto loadA = [&](int kt) {
#pragma unroll
    for (int it = 0; it < 4; ++it) {
      areg[it][0] = *(const f4*)(pxa[it] + kt);
      areg[it][1] = *(const f4*)(pxa[it] + kt + 4);
    }
  };
  auto writeA = [&](int buf) {
    char* base = (char*)lA + buf * 16384;
#pragma unroll
    for (int it = 0; it < 4; ++it) {
      ushort8 o;
#pragma unroll
      for (int j = 0; j < 4; ++j) {
        o[j] = f2bf(areg[it][0][j]);
        o[4 + j] = f2bf(areg[it][1][j]);
      }
      *(ushort8*)(base + awoff[it]) = o;
    }
  };
  auto stageB = [&](int buf, int kt) {
    char* base = (char*)lB + buf * 16384;
#pragma unroll
    for (int it = 0; it < 4; ++it)
      gl_lds16(pxb[it] + kt, base + bwoff[it]);
  };

  const f32x4 Z4 = {0.f, 0.f, 0.f, 0.f};
  f32x4 acc[4][4];
#pragma unroll
  for (int m = 0; m < 4; ++m)
#pragma unroll
    for (int n = 0; n < 4; ++n) acc[m][n] = Z4;

  // read-side thread-constant pieces
  const int rkey = (lo & 7) << 4;
  const int arow = (wr * 64 + lo) * 128;   // + m*2048
  const int brow = (wc * 64 + lo) * 128;   // + n*2048

  loadA(0);
  stageB(0, 0);
  writeA(0);
  __syncthreads();

  int cur = 0;
  for (int t = 0; t < 6; ++t) {
    if (t < 5) {
      loadA((t + 1) * 64);
      stageB(cur ^ 1, (t + 1) * 64);
    }
    const char* bA = (const char*)lA + cur * 16384;
    const char* bB = (const char*)lB + cur * 16384;
#pragma unroll
    for (int s = 0; s < 2; ++s) {
      const int so = (s * 64 + hi * 16) ^ rkey;
      short8 af[4], bf[4];
#pragma unroll
      for (int m = 0; m < 4; ++m) af[m] = *(const short8*)(bA + arow + m * 2048 + so);
#pragma unroll
      for (int n = 0; n < 4; ++n) bf[n] = *(const short8*)(bB + brow + n * 2048 + so);
#pragma unroll
      for (int m = 0; m < 4; ++m)
#pragma unroll
        for (int n = 0; n < 4; ++n)
          acc[m][n] = __builtin_amdgcn_mfma_f32_16x16x32_bf16(af[m], bf[n], acc[m][n], 0, 0, 0);
    }
    if (t < 5) writeA(cur ^ 1);
    __syncthreads();
    cur ^= 1;
  }

  // bias
  float bs[4];
#pragma unroll
  for (int n = 0; n < 4; ++n) bs[n] = bias[n0 + wc * 64 + n * 16 + lo];

  // repack C tile into LDS (bf16), then wide coalesced scatter
  u16* cw = Cs + (size_t)(wr * 64 + hi * 4) * 128 + wc * 64 + lo;
#pragma unroll
  for (int m = 0; m < 4; ++m)
#pragma unroll
    for (int n = 0; n < 4; ++n)
#pragma unroll
      for (int r = 0; r < 4; ++r)
        cw[m * 2048 + r * 128 + n * 16] = f2bf(acc[m][n][r] + bs[n]);
  __syncthreads();

  const int region = n0 / 384;           // 0:q  1:k  2:v
  const int nbase = n0 % 384;
  if (region < 2) {
    u16* dst = region ? oK : oQ;
#pragma unroll
    for (int it = 0; it < 8; ++it) {
      int c = tid + it * 256;            // 2048 chunks of 16B
      int rho = c >> 4, c16 = c & 15;
      short8 v = *(const short8*)((const char*)Cs + rho * 256 + c16 * 16);
      int gm = m0 + rho;
      int b = gm >> 8, tt = gm & 255;
      int hc = nbase + c16 * 8;
      int hh = hc >> 6, d0 = hc & 63;
      *(short8*)(dst + ((size_t)((b * 6 + hh) << 8 | tt) << 6) + d0) = v;
    }
  } else {
    // vT [b,h,d,t]: row-wise gather from Cs, 128B per thread
    const int chi = tid & 127;           // d-direction col in tile
    const int tr0 = (tid >> 7) * 64;     // t-direction row half
    int hc = nbase + chi;
    int hh = hc >> 6, d = hc & 63;
    int b = m0 >> 8;
    int tg0 = (m0 & 255) + tr0;
    u16* dst = oVT + ((size_t)((b * 6 + hh) << 6 | d) << 8) + tg0;
#pragma unroll
    for (int s = 0; s < 8; ++s) {
      ushort8 v;
#pragma unroll
      for (int j = 0; j < 8; ++j)
        v[j] = Cs[(tr0 + s * 8 + j) * 128 + chi];
      *(ushort8*)(dst + s * 8) = v;
    }
  }
}

// ---------------- GEMM2: out = att(bf16) @ pT^T + proj_b (f32 out) ----------------
__global__ __launch_bounds__(256) void gemm_proj_k(
    const u16* __restrict__ A, const u16* __restrict__ Bt,
    const float* __restrict__ bias, float* __restrict__ oF) {
  constexpr int K = 384, N = 384, NTN = 3;
  __shared__ char smem[65536];
  u16* lA = (u16*)smem;
  u16* lB = (u16*)(smem + 32768);

  const int tid = threadIdx.x;
  const int per = gridDim.x >> 3;
  const int idx = (blockIdx.x & 7) * per + (blockIdx.x >> 3);
  const int m0 = (idx / NTN) * 128;
  const int n0 = (idx % NTN) * 128;
  const int lane = tid & 63, wid = tid >> 6;
  const int lo = lane & 15, hi = lane >> 4;
  const int wr = wid >> 1, wc = wid & 1;

  const int rb = tid >> 3;
  const int cb = tid & 7;
  const int csb = cb ^ (rb & 7);

  const u16* pxa[4];
  const u16* pxb[4];
  int woff[4];
#pragma unroll
  for (int it = 0; it < 4; ++it) {
    pxa[it] = A + (size_t)(m0 + rb + it * 32) * K + csb * 8;
    pxb[it] = Bt + (size_t)(n0 + rb + it * 32) * K + csb * 8;
    woff[it] = (tid + it * 256) * 16;
  }

  auto stage = [&](int buf, int kt) {
    char* ba = (char*)lA + buf * 16384;
    char* bb = (char*)lB + buf * 16384;
#pragma unroll
    for (int it = 0; it < 4; ++it) {
      gl_lds16(pxa[it] + kt, ba + woff[it]);
      gl_lds16(pxb[it] + kt, bb + woff[it]);
    }
  };

  const f32x4 Z4 = {0.f, 0.f, 0.f, 0.f};
  f32x4 acc[4][4];
#pragma unroll
  for (int m = 0; m < 4; ++m)
#pragma unroll
    for (int n = 0; n < 4; ++n) acc[m][n] = Z4;

  const int rkey = (lo & 7) << 4;
  const int arow = (wr * 64 + lo) * 128;
  const int brow = (wc * 64 + lo) * 128;

  stage(0, 0);
  __syncthreads();
  int cur = 0;
  for (int t = 0; t < 6; ++t) {
    if (t < 5) stage(cur ^ 1, (t + 1) * 64);
    const char* bA = (const char*)lA + cur * 16384;
    const char* bB = (const char*)lB + cur * 16384;
#pragma unroll
    for (int s = 0; s < 2; ++s) {
      const int so = (s * 64 + hi * 16) ^ rkey;
      short8 af[4], bf[4];
#pragma unroll
      for (int m = 0; m < 4; ++m) af[m] = *(const short8*)(bA + arow + m * 2048 + so);
#pragma unroll
      for (int n = 0; n < 4; ++n) bf[n] = *(const short8*)(bB + brow + n * 2048 + so);
#pragma unroll
      for (int m = 0; m < 4; ++m)
#pragma unroll
        for (int n = 0; n < 4; ++n)
          acc[m][n] = __builtin_amdgcn_mfma_f32_16x16x32_bf16(af[m], bf[n], acc[m][n], 0, 0, 0);
    }
    __syncthreads();
    cur ^= 1;
  }

  float bs[4];
#pragma unroll
  for (int n = 0; n < 4; ++n) bs[n] = bias[n0 + wc * 64 + n * 16 + lo];
  const int rbase = m0 + wr * 64;
  const int cbase = n0 + wc * 64;
#pragma unroll
  for (int n = 0; n < 4; ++n) {
    int gn = cbase + n * 16 + lo;
#pragma unroll
    for (int m = 0; m < 4; ++m)
#pragma unroll
      for (int r = 0; r < 4; ++r) {
        int gm = rbase + m * 16 + hi * 4 + r;
        oF[(size_t)gm * N + gn] = acc[m][n][r] + bs[n];
      }
  }
}

// ---------------- windowed causal attention ----------------
__global__ __launch_bounds__(256) void attn_k(
    const u16* __restrict__ Qb, const u16* __restrict__ Kb,
    const u16* __restrict__ VTb, const float* __restrict__ gate,
    u16* __restrict__ Ao) {
  __shared__ u16 Ks[128 * 64];      // [key][d]   swizzled, 16KB
  __shared__ u16 Vs[64 * 128];      // [d][key]   swizzled, 16KB
  __shared__ u16 Ps[4][16 * 128];   // per-wave P [q][key] swizzled, 16KB
  const int bx = blockIdx.x;
  const int qt = bx & 3, bh = bx >> 2;
  const int h = bh % 6, b = bh / 6;
  const int i0 = qt * 64, j0 = i0 - 64;
  const int tid = threadIdx.x, w = tid >> 6, lane = tid & 63;
  const int lo = lane & 15, hi = lane >> 4;

  const u16* Kh = Kb + (size_t)bh * (256 * 64);
  const u16* Vh = VTb + (size_t)bh * (64 * 256);
  const u16* Qh = Qb + (size_t)bh * (256 * 64);

#pragma unroll
  for (int it = 0; it < 4; ++it) {
    int chunk = tid + it * 256;
    int row = chunk >> 3, cc = chunk & 7;
    int csrc = cc ^ (row & 7);
    int j = j0 + row; if (j < 0) j = 0;
    gl_lds16(Kh + j * 64 + csrc * 8, Ks + chunk * 8);
  }
#pragma unroll
  for (int it = 0; it < 4; ++it) {
    int chunk = tid + it * 256;
    int d = chunk >> 4, kc = chunk & 15;
    int ksrc = kc ^ (d & 7);
    int j = j0 + ksrc * 8; if (j < 0) j = 0;
    gl_lds16(Vh + d * 256 + j, Vs + chunk * 8);
  }

  const int iq = i0 + w * 16 + lo;
  short8 aq0 = *(const short8*)(Qh + iq * 64 + hi * 8);
  short8 aq1 = *(const short8*)(Qh + iq * 64 + 32 + hi * 8);

  __syncthreads();

  const f32x4 Z4 = {0.f, 0.f, 0.f, 0.f};
  f32x4 accS[8];
#pragma unroll
  for (int t = 0; t < 8; ++t) accS[t] = Z4;
#pragma unroll
  for (int t = 0; t < 8; ++t) {
    int key = t * 16 + lo;
    int base = key * 128;
    int sw = (key & 7) << 4;
    short8 bk0 = *(const short8*)((const char*)Ks + ((base + hi * 16) ^ sw));
    short8 bk1 = *(const short8*)((const char*)Ks + ((base + 64 + hi * 16) ^ sw));
    accS[t] = __builtin_amdgcn_mfma_f32_16x16x32_bf16(aq0, bk0, accS[t], 0, 0, 0);
    accS[t] = __builtin_amdgcn_mfma_f32_16x16x32_bf16(aq1, bk1, accS[t], 0, 0, 0);
  }

  float pv[4][8];
  float rinv[4];
#pragma unroll
  for (int r = 0; r < 4; ++r) {
    int i = i0 + w * 16 + hi * 4 + r;
    float mx = -1e30f;
    float vals[8];
#pragma unroll
    for (int t = 0; t < 8; ++t) {
      int j = j0 + t * 16 + lo;
      float s = accS[t][r] * 0.125f;
      bool ok = (j >= 0) && (j <= i) && (j >= i - 64);
      vals[t] = ok ? s : -1e30f;
      mx = fmaxf(mx, vals[t]);
    }
#pragma unroll
    for (int off = 1; off < 16; off <<= 1) mx = fmaxf(mx, __shfl_xor(mx, off));
    float sum = 0.f;
#pragma unroll
    for (int t = 0; t < 8; ++t) {
      float p = __expf(vals[t] - mx);
      pv[r][t] = p;
      sum += p;
    }
#pragma unroll
    for (int off = 1; off < 16; off <<= 1) sum += __shfl_xor(sum, off);
    rinv[r] = 1.0f / sum;
  }

  u16* Pw = Ps[w];
#pragma unroll
  for (int r = 0; r < 4; ++r) {
    int ql = hi * 4 + r;
    int sw = (ql & 7) << 4;
#pragma unroll
    for (int t = 0; t < 8; ++t) {
      int off = (ql * 256 + (t * 16 + lo) * 2) ^ sw;
      *(u16*)((char*)Pw + off) = f2bf(pv[r][t]);
    }
  }

  f32x4 accO[4];
#pragma unroll
  for (int dt = 0; dt < 4; ++dt) accO[dt] = Z4;
#pragma unroll
  for (int ks = 0; ks < 4; ++ks) {
    int offA = (lo * 256 + ks * 64 + hi * 16) ^ ((lo & 7) << 4);
    short8 ap = *(const short8*)((const char*)Pw + offA);
#pragma unroll
    for (int dt = 0; dt < 4; ++dt) {
      int d = dt * 16 + lo;
      int offB = (d * 256 + ks * 64 + hi * 16) ^ ((d & 7) << 4);
      short8 bv = *(const short8*)((const char*)Vs + offB);
      accO[dt] = __builtin_amdgcn_mfma_f32_16x16x32_bf16(ap, bv, accO[dt], 0, 0, 0);
    }
  }

#pragma unroll
  for (int dt = 0; dt < 4; ++dt) {
    int d = dt * 16 + lo;
    float gg = gate[h * 64 + d];
#pragma unroll
    for (int r = 0; r < 4; ++r) {
      int i = i0 + w * 16 + hi * 4 + r;
      float v = accO[dt][r] * rinv[r] * gg;
      Ao[(size_t)(b * 256 + i) * 384 + h * 64 + d] = f2bf(v);
    }
  }
}

// ---------------- launch ----------------
extern "C" void kernel_launch(void* const* d_in, const int* in_sizes, int n_in,
                              void* d_out, int out_size, void* d_ws, size_t ws_size,
                              hipStream_t stream) {
  const float* x      = (const float*)d_in[0];
  const float* qkv_w  = (const float*)d_in[1];
  const float* qkv_b  = (const float*)d_in[2];
  const float* proj_w = (const float*)d_in[3];
  const float* proj_b = (const float*)d_in[4];
  const float* gate   = (const float*)d_in[5];
  float* out = (float*)d_out;

  // ws layout:
  //   [0, 50331648)            att (attention output, bf16)
  //   [50331648, 100663296)    vT  [B,H,64,T] bf16
  //   [100663296, 101548032)   w1T [1152,384] bf16
  //   [101548032, 101842944)   pT  [384,384]  bf16
  char* ws = (char*)d_ws;
  u16* att  = (u16*)ws;
  u16* vT   = (u16*)(ws + 50331648);
  u16* w1T  = (u16*)(ws + 100663296);
  u16* pT   = (u16*)(ws + 101548032);
  // d_out doubles as q+k scratch until GEMM2 overwrites it
  u16* qbuf = (u16*)d_out;
  u16* kbuf = (u16*)((char*)d_out + 50331648);

  transpose_cvt_k<<<dim3(1152 / 32, 384 / 32), dim3(32, 8), 0, stream>>>(qkv_w, w1T, 384, 1152);
  transpose_cvt_k<<<dim3(384 / 32, 384 / 32), dim3(32, 8), 0, stream>>>(proj_w, pT, 384, 384);

  gemm_qkv_k<<<4608, 256, 0, stream>>>(x, w1T, qkv_b, qbuf, kbuf, vT);
  attn_k<<<256 * 6 * 4, 256, 0, stream>>>(qbuf, kbuf, vT, gate, att);
  gemm_proj_k<<<1536, 256, 0, stream>>>(att, pT, proj_b, out);
}